// Round 7
// baseline (207.101 us; speedup 1.0000x reference)
//
#include <hip/hip_runtime.h>
#include <cmath>

#define NB 256
#define NS 8192
#define NF 2048
#define NK 20

typedef _Float16 half8 __attribute__((ext_vector_type(8)));
typedef _Float16 half4 __attribute__((ext_vector_type(4)));
typedef float f32x4 __attribute__((ext_vector_type(4)));

__device__ __forceinline__ void async16(const void* g, void* l) {
  __builtin_amdgcn_global_load_lds(
      (const __attribute__((address_space(1))) unsigned int*)g,
      (__attribute__((address_space(3))) unsigned int*)l, 16, 0, 0);
}

__device__ __forceinline__ float waveSum(float v) {
#pragma unroll
  for (int off = 32; off > 0; off >>= 1) v += __shfl_xor(v, off, 64);
  return v;
}
__device__ __forceinline__ float waveMax(float v) {
#pragma unroll
  for (int off = 32; off > 0; off >>= 1) v = fmaxf(v, __shfl_xor(v, off, 64));
  return v;
}

// ============ K1: prep ============
// blocks [0,512): FUSED row stats + raw-exp P write (one logits pass).
// blocks [512,768): normalize x -> xh fp16.
__global__ __launch_bounds__(256) void prep(
    const float* __restrict__ in0, const float* __restrict__ logits0,
    const float* __restrict__ logits1, _Float16* __restrict__ P,
    _Float16* __restrict__ xh, float* __restrict__ alpha,
    float* __restrict__ mll, float* __restrict__ loss) {
  __shared__ float redA[4], redB[4];
  int tid = threadIdx.x, blk = blockIdx.x;
  int wave = tid >> 6, lane = tid & 63;

  if (blk < 512) {
    if (blk == 0 && tid < 3) loss[tid] = 0.0f;  // zero loss accumulators
    int r = blk;
    const float* src = (r < NB) ? logits0 : logits1;
    const float4* row = (const float4*)(src + (size_t)(r & (NB - 1)) * NS);
    float4 v[8];
    float mx = -1e30f;
#pragma unroll
    for (int i = 0; i < 8; ++i) {
      v[i] = row[tid + i * 256];
      mx = fmaxf(mx, fmaxf(fmaxf(v[i].x, v[i].y), fmaxf(v[i].z, v[i].w)));
    }
    float wv = waveMax(mx);
    if (lane == 0) redA[wave] = wv;
    __syncthreads();
    float m = fmaxf(fmaxf(redA[0], redA[1]), fmaxf(redA[2], redA[3]));
    float em = expf(m);
    float se = 0.0f;
    half4* prow = (half4*)(P + (size_t)r * NS);
#pragma unroll
    for (int i = 0; i < 8; ++i) {
      float e0 = expf(v[i].x - m), e1 = expf(v[i].y - m);
      float e2 = expf(v[i].z - m), e3 = expf(v[i].w - m);
      se += (e0 + e1) + (e2 + e3);
      half4 h;
      h[0] = (_Float16)(e0 * em); h[1] = (_Float16)(e1 * em);
      h[2] = (_Float16)(e2 * em); h[3] = (_Float16)(e3 * em);
      prow[tid + i * 256] = h;
    }
    float sw = waveSum(se);
    if (lane == 0) redB[wave] = sw;
    __syncthreads();
    float l = (redB[0] + redB[1]) + (redB[2] + redB[3]);
    if (tid == 0) {
      mll[r] = m + logf(l);
      alpha[r] = 256.0f * expf(-m) / l;
    }
  } else {
    // ---- normalize x -> xh ----
    int b = blk - 512;
    const float4* row = (const float4*)(in0 + (size_t)b * NF);
    float4 v0 = row[tid], v1 = row[tid + 256];
    float ss = v0.x * v0.x + v0.y * v0.y + v0.z * v0.z + v0.w * v0.w +
               v1.x * v1.x + v1.y * v1.y + v1.z * v1.z + v1.w * v1.w;
    float w = waveSum(ss);
    if (lane == 0) redA[wave] = w;
    __syncthreads();
    float tot = (redA[0] + redA[1]) + (redA[2] + redA[3]);
    float inv = 1.0f / fmaxf(sqrtf(tot), 1e-12f);
    half4 h0, h1;
    h0[0] = (_Float16)(v0.x * inv); h0[1] = (_Float16)(v0.y * inv);
    h0[2] = (_Float16)(v0.z * inv); h0[3] = (_Float16)(v0.w * inv);
    h1[0] = (_Float16)(v1.x * inv); h1[1] = (_Float16)(v1.y * inv);
    h1[2] = (_Float16)(v1.z * inv); h1[3] = (_Float16)(v1.w * inv);
    ((half4*)(xh + (size_t)b * NF))[tid] = h0;
    ((half4*)(xh + (size_t)b * NF))[tid + 256] = h1;
  }
}

// ============ K2: GEMM1 (pipelined dbuf, 1 barrier/iter) + sparse gather ============
// blocks [0,256): scores = x@F^T. Tile M=128 x N=64, BK=64, double-buffered
//   LDS, ONE barrier per K-step: issue fv(k+1) + async16 A(k+1) at top (full
//   MFMA phase to resolve), consume fv at bottom (ds_write + outF store),
//   then barrier. XCD-pair swizzle: blk and blk^8 share the features stripe.
// blocks [256,1280): gather block (b, s-slice): sparse 20-neighbor weighted
//   sums over P rows, fused CE/KL epilogue, atomicAdd out[1],out[2].
__global__ __launch_bounds__(256) void fused2(
    const _Float16* __restrict__ xh, const float* __restrict__ fB,
    const _Float16* __restrict__ P, const float* __restrict__ alpha,
    const float* __restrict__ mll, const float* __restrict__ logits0,
    const float* __restrict__ logits1, const int* __restrict__ targets,
    const int* __restrict__ neighbors, const float* __restrict__ ndist,
    const float* __restrict__ rampup, float* __restrict__ outF,
    float* __restrict__ pm, float* __restrict__ pl, float* __restrict__ tgt,
    float* __restrict__ out) {
  __shared__ alignas(16) _Float16 As[2][128 * 64];  // 32 KB
  __shared__ alignas(16) _Float16 Bs[2][64 * 64];   // 16 KB
  __shared__ float red[8];
  int tid = threadIdx.x, wave = tid >> 6, lane = tid & 63;
  int quad = lane >> 4, r16 = lane & 15;
  int blk = blockIdx.x;

  if (blk < 256) {
    // XCD-pair swizzle: by from bit3 so (blk, blk^8) share bx on one XCD (%8)
    int by = (blk >> 3) & 1;
    int bx = (blk & 7) | ((blk >> 4) << 3);
    int n0 = bx * 64, m0 = by * 128;
    int brow = tid >> 2, bcg = tid & 3;  // B staging: row (64), 16-float group
    const float* bsrc = fB + (size_t)(n0 + brow) * NF + bcg * 16;

    auto loadA = [&](int kel, int bufi) {
#pragma unroll
      for (int ss = 0; ss < 4; ++ss) {
        int rl = ss * 32 + (tid >> 3);
        int sc = (tid & 7) ^ (rl & 7);
        async16(xh + (size_t)(m0 + rl) * NF + kel + sc * 8,
                &As[bufi][rl * 64 + (tid & 7) * 8]);
      }
    };
    float4 fv[4];
    auto writeB = [&](int bufi) {
#pragma unroll
      for (int h = 0; h < 2; ++h) {
        half8 hh;
        hh[0] = (_Float16)fv[2 * h].x; hh[1] = (_Float16)fv[2 * h].y;
        hh[2] = (_Float16)fv[2 * h].z; hh[3] = (_Float16)fv[2 * h].w;
        hh[4] = (_Float16)fv[2 * h + 1].x; hh[5] = (_Float16)fv[2 * h + 1].y;
        hh[6] = (_Float16)fv[2 * h + 1].z; hh[7] = (_Float16)fv[2 * h + 1].w;
        int c8 = bcg * 2 + h;
        *(half8*)&Bs[bufi][brow * 64 + ((c8 ^ (brow & 7)) << 3)] = hh;
      }
    };
    auto storeO = [&](int kel) {
      float4* odst = (float4*)(outF + (size_t)(n0 + brow) * NF + kel + bcg * 16);
#pragma unroll
      for (int q = 0; q < 4; ++q) odst[q] = fv[q];
    };

    f32x4 acc[2][4] = {};
    // prologue: stage tile 0
#pragma unroll
    for (int q = 0; q < 4; ++q) fv[q] = *(const float4*)(bsrc + q * 4);
    loadA(0, 0);
    writeB(0);
    if (by == 0) storeO(0);
    __syncthreads();

    for (int k = 0; k < 32; ++k) {
      int buf = k & 1;
      int kn = (k + 1) * 64;
      if (kn < NF) {
        // issue next tile's loads FIRST: full MFMA phase hides HBM latency
#pragma unroll
        for (int q = 0; q < 4; ++q) fv[q] = *(const float4*)(bsrc + kn + q * 4);
        loadA(kn, buf ^ 1);
      }
      // MFMA on current buffer
#pragma unroll
      for (int sub = 0; sub < 2; ++sub) {
        int slot = ((sub * 4 + quad) ^ (r16 & 7)) * 8;
        half8 af[2], bf[4];
#pragma unroll
        for (int i = 0; i < 2; ++i)
          af[i] = *(const half8*)&As[buf][(wave * 32 + i * 16 + r16) * 64 + slot];
#pragma unroll
        for (int j = 0; j < 4; ++j)
          bf[j] = *(const half8*)&Bs[buf][(j * 16 + r16) * 64 + slot];
#pragma unroll
        for (int i = 0; i < 2; ++i)
#pragma unroll
          for (int j = 0; j < 4; ++j)
            acc[i][j] = __builtin_amdgcn_mfma_f32_16x16x32_f16(af[i], bf[j], acc[i][j], 0, 0, 0);
      }
      if (kn < NF) {
        writeB(buf ^ 1);
        if (by == (kn >= NF / 2 ? 1 : 0)) storeO(kn);
        __syncthreads();  // one barrier per K-step
      }
    }
    // epilogue: per-row LSE over this block's 64 cols -> stripe bx
#pragma unroll
    for (int i = 0; i < 2; ++i)
#pragma unroll
      for (int r = 0; r < 4; ++r) {
        int R = m0 + wave * 32 + i * 16 + quad * 4 + r;
        float sv[4];
#pragma unroll
        for (int j = 0; j < 4; ++j) sv[j] = acc[i][j][r] * 20.0f;  // 1/TEMP
        float mx = fmaxf(fmaxf(sv[0], sv[1]), fmaxf(sv[2], sv[3]));
#pragma unroll
        for (int m2 = 1; m2 < 16; m2 <<= 1) mx = fmaxf(mx, __shfl_xor(mx, m2, 64));
        float e = expf(sv[0] - mx) + expf(sv[1] - mx) + expf(sv[2] - mx) + expf(sv[3] - mx);
#pragma unroll
        for (int m2 = 1; m2 < 16; m2 <<= 1) e += __shfl_xor(e, m2, 64);
        int tg = targets[R];
#pragma unroll
        for (int j = 0; j < 4; ++j)
          if (n0 + j * 16 + r16 == tg) tgt[R] = sv[j];
        if (r16 == 0) { pm[R * 128 + bx] = mx; pl[R * 128 + bx] = e; }
      }
  } else {
    // ---- sparse neighbor-gather CE/KL ----
    int gb = blk - 256;
    int b = gb >> 2, s0 = (gb & 3) * 2048;
    float s = 0.0f;
    int cnt = 0;
#pragma unroll
    for (int k = 0; k < NK; ++k) {
      float d = ndist[b * NK + k];
      s += expf(d * (1.0f / 0.6f));
      cnt += (d <= 2.0f) ? 1 : 0;
    }
    float invs = 1.0f / (2.0f * s);
    float invc = 1.0f / fmaxf((float)cnt, 1.0f);
    float ce[8] = {0, 0, 0, 0, 0, 0, 0, 0};
    float kl[8] = {0, 0, 0, 0, 0, 0, 0, 0};
    int sc_ = s0 + tid * 8;
#pragma unroll 4
    for (int k = 0; k < NK; ++k) {
      float d = ndist[b * NK + k];
      int n = neighbors[b * NK + k];
      float wce = expf(d * (1.0f / 0.6f)) * invs;
      float wkl = (d <= 2.0f) ? invc : 0.0f;
      float a0 = alpha[n], a1 = alpha[256 + n];
      float c0 = wce * a0, c1 = wce * a1, ck = wkl * a0;
      half8 p0 = *(const half8*)(P + (size_t)n * NS + sc_);
      half8 p1 = *(const half8*)(P + (size_t)(256 + n) * NS + sc_);
#pragma unroll
      for (int e2 = 0; e2 < 8; ++e2) {
        float q0 = (float)p0[e2], q1 = (float)p1[e2];
        ce[e2] += c0 * q0 + c1 * q1;
        kl[e2] += ck * q0;
      }
    }
    float mv0 = mll[b], mv1 = mll[256 + b];
    const float* g0 = logits0 + (size_t)b * NS + sc_;
    const float* g1 = logits1 + (size_t)b * NS + sc_;
    float4 l0a = *(const float4*)g0, l0b = *(const float4*)(g0 + 4);
    float4 l1a = *(const float4*)g1, l1b = *(const float4*)(g1 + 4);
    float lg0[8] = {l0a.x, l0a.y, l0a.z, l0a.w, l0b.x, l0b.y, l0b.z, l0b.w};
    float lg1[8] = {l1a.x, l1a.y, l1a.z, l1a.w, l1b.x, l1b.y, l1b.z, l1b.w};
    float lce = 0.0f, lkl = 0.0f;
#pragma unroll
    for (int e2 = 0; e2 < 8; ++e2) {
      float t = ce[e2] * (1.0f / 256.0f);
      lce += t * (lg0[e2] - mv0);
      float tk = kl[e2] * (1.0f / 256.0f);
      lkl += (tk > 0.0f) ? tk * (logf(fmaxf(tk, 1e-12f)) - (lg1[e2] - mv1)) : 0.0f;
    }
    float wc = waveSum(lce), wk = waveSum(lkl);
    if (lane == 0) { red[wave] = wc; red[4 + wave] = wk; }
    __syncthreads();
    if (tid == 0) {
      float ce_t = (red[0] + red[1]) + (red[2] + red[3]);
      float kl_t = (red[4] + red[5]) + (red[6] + red[7]);
      atomicAdd(out + 1, -0.1f * ce_t * (1.0f / 256.0f));
      atomicAdd(out + 2, rampup[0] * kl_t * (1.0f / 256.0f));
    }
  }
}

// ============ K3: finalize + momentum winner rows ============
__global__ __launch_bounds__(128) void final_reduce(
    const float* __restrict__ pm, const float* __restrict__ pl,
    const float* __restrict__ tgt, const float* __restrict__ logits0,
    const float* __restrict__ mll, const int* __restrict__ targets,
    const float* __restrict__ in0, const float* __restrict__ features,
    float* __restrict__ outF, float* __restrict__ out) {
  __shared__ float rA[2], rB[2];
  __shared__ int flag;
  int tid = threadIdx.x, blk = blockIdx.x;
  if (blk < 256) {
    int b = blk;
    float m = pm[b * 128 + tid];
    float l = pl[b * 128 + tid];
    float wm = waveMax(m);
    if ((tid & 63) == 0) rA[tid >> 6] = wm;
    __syncthreads();
    float mx = fmaxf(rA[0], rA[1]);
    float e = l * expf(m - mx);
    float ws = waveSum(e);
    if ((tid & 63) == 0) rB[tid >> 6] = ws;
    __syncthreads();
    if (tid == 0) {
      float S = rB[0] + rB[1];
      float nce = -(tgt[b] - mx - logf(S));
      int tg = targets[b];
      float oh = -0.9f * (logits0[(size_t)b * NS + tg] - mll[b]);
      atomicAdd(out + 0, nce * (1.0f / 256.0f));
      atomicAdd(out + 1, oh * (1.0f / 256.0f));
    }
  } else {
    int b = blk - 256;
    int tg = targets[b];
    if (tid == 0) flag = 0;
    __syncthreads();
    bool later = false;
    for (int i = b + 1 + tid; i < 256; i += 128) later = later || (targets[i] == tg);
    if (later) flag = 1;
    __syncthreads();
    if (flag) return;  // some later batch row owns this target
    const float4* xr = (const float4*)(in0 + (size_t)b * NF);
    const float4* fr = (const float4*)(features + (size_t)tg * NF);
    float4 a[4];
    float ssx = 0.0f;
#pragma unroll
    for (int s = 0; s < 4; ++s) {
      a[s] = xr[tid + s * 128];
      ssx += a[s].x * a[s].x + a[s].y * a[s].y + a[s].z * a[s].z + a[s].w * a[s].w;
    }
    float w1 = waveSum(ssx);
    if ((tid & 63) == 0) rA[tid >> 6] = w1;
    __syncthreads();
    float ix = 0.8f / fmaxf(sqrtf(rA[0] + rA[1]), 1e-12f);
    float4 v[4];
    float ss = 0.0f;
#pragma unroll
    for (int s = 0; s < 4; ++s) {
      float4 f = fr[tid + s * 128];
      v[s] = make_float4(0.2f * f.x + ix * a[s].x, 0.2f * f.y + ix * a[s].y,
                         0.2f * f.z + ix * a[s].z, 0.2f * f.w + ix * a[s].w);
      ss += v[s].x * v[s].x + v[s].y * v[s].y + v[s].z * v[s].z + v[s].w * v[s].w;
    }
    float w2 = waveSum(ss);
    if ((tid & 63) == 0) rB[tid >> 6] = w2;
    __syncthreads();
    float inv = 1.0f / fmaxf(sqrtf(rB[0] + rB[1]), 1e-12f);
    float4* o4 = (float4*)(outF + (size_t)tg * NF);
#pragma unroll
    for (int s = 0; s < 4; ++s)
      o4[tid + s * 128] = make_float4(v[s].x * inv, v[s].y * inv, v[s].z * inv, v[s].w * inv);
  }
}

extern "C" void kernel_launch(void* const* d_in, const int* in_sizes, int n_in,
                              void* d_out, int out_size, void* d_ws, size_t ws_size,
                              hipStream_t stream) {
  const float* inputs0 = (const float*)d_in[0];
  const float* logits0 = (const float*)d_in[1];
  const float* logits1 = (const float*)d_in[2];
  const int* targets = (const int*)d_in[3];
  const int* neighbors = (const int*)d_in[5];
  const float* ndist = (const float*)d_in[6];
  const float* rampup = (const float*)d_in[7];
  const float* features = (const float*)d_in[8];
  float* out = (float*)d_out;

  char* ws = (char*)d_ws;
  float* mll = (float*)(ws + 4096);            // 2 KB
  float* alpha = (float*)(ws + 8192);          // 2 KB (f32)
  float* tgt = (float*)(ws + 16384);           // 1 KB
  float* pm = (float*)(ws + 65536);            // 128 KB (256 rows x 128 stripes)
  float* pl = (float*)(ws + 196608);           // 128 KB
  _Float16* xh = (_Float16*)(ws + (3 << 20));  // 1 MB
  _Float16* P = (_Float16*)(ws + (4 << 20));   // 8 MB (row-major raw exp)

  prep<<<768, 256, 0, stream>>>(inputs0, logits0, logits1, P, xh, alpha, mll, out);
  fused2<<<1280, 256, 0, stream>>>(xh, features, P, alpha, mll, logits0, logits1,
                                   targets, neighbors, ndist, rampup, out + 3,
                                   pm, pl, tgt, out);
  final_reduce<<<512, 128, 0, stream>>>(pm, pl, tgt, logits0, mll, targets,
                                        inputs0, features, out + 3, out);
}

// Round 8
// 204.976 us; speedup vs baseline: 1.0104x; 1.0104x over previous
//
#include <hip/hip_runtime.h>
#include <cmath>

#define NB 256
#define NS 8192
#define NF 2048
#define NK 20

typedef _Float16 half8 __attribute__((ext_vector_type(8)));
typedef _Float16 half4 __attribute__((ext_vector_type(4)));
typedef float f32x4 __attribute__((ext_vector_type(4)));

__device__ __forceinline__ void async16(const void* g, void* l) {
  __builtin_amdgcn_global_load_lds(
      (const __attribute__((address_space(1))) unsigned int*)g,
      (__attribute__((address_space(3))) unsigned int*)l, 16, 0, 0);
}

__device__ __forceinline__ float waveSum(float v) {
#pragma unroll
  for (int off = 32; off > 0; off >>= 1) v += __shfl_xor(v, off, 64);
  return v;
}
__device__ __forceinline__ float waveMax(float v) {
#pragma unroll
  for (int off = 32; off > 0; off >>= 1) v = fmaxf(v, __shfl_xor(v, off, 64));
  return v;
}

// ============ K1: prep ============
// blocks [0,512): FUSED row stats + raw-exp P write (one logits pass).
// blocks [512,768): normalize x -> xh fp16.
__global__ __launch_bounds__(256) void prep(
    const float* __restrict__ in0, const float* __restrict__ logits0,
    const float* __restrict__ logits1, _Float16* __restrict__ P,
    _Float16* __restrict__ xh, float* __restrict__ alpha,
    float* __restrict__ mll, float* __restrict__ loss) {
  __shared__ float redA[4], redB[4];
  int tid = threadIdx.x, blk = blockIdx.x;
  int wave = tid >> 6, lane = tid & 63;

  if (blk < 512) {
    if (blk == 0 && tid < 3) loss[tid] = 0.0f;  // zero loss accumulators
    int r = blk;
    const float* src = (r < NB) ? logits0 : logits1;
    const float4* row = (const float4*)(src + (size_t)(r & (NB - 1)) * NS);
    float4 v[8];
    float mx = -1e30f;
#pragma unroll
    for (int i = 0; i < 8; ++i) {
      v[i] = row[tid + i * 256];
      mx = fmaxf(mx, fmaxf(fmaxf(v[i].x, v[i].y), fmaxf(v[i].z, v[i].w)));
    }
    float wv = waveMax(mx);
    if (lane == 0) redA[wave] = wv;
    __syncthreads();
    float m = fmaxf(fmaxf(redA[0], redA[1]), fmaxf(redA[2], redA[3]));
    float em = expf(m);
    float se = 0.0f;
    half4* prow = (half4*)(P + (size_t)r * NS);
#pragma unroll
    for (int i = 0; i < 8; ++i) {
      float e0 = expf(v[i].x - m), e1 = expf(v[i].y - m);
      float e2 = expf(v[i].z - m), e3 = expf(v[i].w - m);
      se += (e0 + e1) + (e2 + e3);
      half4 h;
      h[0] = (_Float16)(e0 * em); h[1] = (_Float16)(e1 * em);
      h[2] = (_Float16)(e2 * em); h[3] = (_Float16)(e3 * em);
      prow[tid + i * 256] = h;
    }
    float sw = waveSum(se);
    if (lane == 0) redB[wave] = sw;
    __syncthreads();
    float l = (redB[0] + redB[1]) + (redB[2] + redB[3]);
    if (tid == 0) {
      mll[r] = m + logf(l);
      alpha[r] = 256.0f * expf(-m) / l;
    }
  } else {
    // ---- normalize x -> xh ----
    int b = blk - 512;
    const float4* row = (const float4*)(in0 + (size_t)b * NF);
    float4 v0 = row[tid], v1 = row[tid + 256];
    float ss = v0.x * v0.x + v0.y * v0.y + v0.z * v0.z + v0.w * v0.w +
               v1.x * v1.x + v1.y * v1.y + v1.z * v1.z + v1.w * v1.w;
    float w = waveSum(ss);
    if (lane == 0) redA[wave] = w;
    __syncthreads();
    float tot = (redA[0] + redA[1]) + (redA[2] + redA[3]);
    float inv = 1.0f / fmaxf(sqrtf(tot), 1e-12f);
    half4 h0, h1;
    h0[0] = (_Float16)(v0.x * inv); h0[1] = (_Float16)(v0.y * inv);
    h0[2] = (_Float16)(v0.z * inv); h0[3] = (_Float16)(v0.w * inv);
    h1[0] = (_Float16)(v1.x * inv); h1[1] = (_Float16)(v1.y * inv);
    h1[2] = (_Float16)(v1.z * inv); h1[3] = (_Float16)(v1.w * inv);
    ((half4*)(xh + (size_t)b * NF))[tid] = h0;
    ((half4*)(xh + (size_t)b * NF))[tid + 256] = h1;
  }
}

// ============ K2: GEMM1 (BK=128, 16 iters, tuned drains) + sparse gather ============
// blocks [0,256): scores = x@F^T. Tile M=128 x N=64, BK=128, single-buffered
//   2-barrier loop; fv(k+1) issued during MFMA phase (drain covered); outF
//   store issued after barrier-b (ack drains at next barrier-a under MFMA).
//   B rows read 128B/thread contiguous; 16-chunk XOR swizzle (c ^ row&7).
// blocks [256,1280): gather block (b, s-slice): sparse 20-neighbor weighted
//   sums over P rows, fused CE/KL epilogue, atomicAdd out[1],out[2].
__global__ __launch_bounds__(256) void fused2(
    const _Float16* __restrict__ xh, const float* __restrict__ fB,
    const _Float16* __restrict__ P, const float* __restrict__ alpha,
    const float* __restrict__ mll, const float* __restrict__ logits0,
    const float* __restrict__ logits1, const int* __restrict__ targets,
    const int* __restrict__ neighbors, const float* __restrict__ ndist,
    const float* __restrict__ rampup, float* __restrict__ outF,
    float* __restrict__ pm, float* __restrict__ pl, float* __restrict__ tgt,
    float* __restrict__ out) {
  __shared__ alignas(16) _Float16 As[128 * 128];  // 32 KB
  __shared__ alignas(16) _Float16 Bs[64 * 128];   // 16 KB
  __shared__ float red[8];
  int tid = threadIdx.x, wave = tid >> 6, lane = tid & 63;
  int quad = lane >> 4, r16 = lane & 15;
  int blk = blockIdx.x;

  if (blk < 256) {
    // XCD-pair swizzle: (blk, blk^8) share the same features stripe
    int by = (blk >> 3) & 1;
    int bx = (blk & 7) | ((blk >> 4) << 3);
    int n0 = bx * 64, m0 = by * 128;
    int brow = tid >> 2, bq = tid & 3;  // B staging: row(64), 32-float group
    const float* bsrc = fB + (size_t)(n0 + brow) * NF + bq * 32;

    float4 fv[8];
    f32x4 acc[2][4] = {};
    // prologue: issue first fv batch (drained at first barrier-a, once)
#pragma unroll
    for (int q = 0; q < 8; ++q) fv[q] = *(const float4*)(bsrc + q * 4);

    for (int k0 = 0; k0 < NF; k0 += 128) {
      __syncthreads();  // (a) prev tile consumed; fv(k0) mostly arrived
      // A tile: 128 rows x 128 cols fp16 via async16, pre-swizzled source
#pragma unroll
      for (int ss = 0; ss < 8; ++ss) {
        int rl = ss * 16 + (tid >> 4);
        int sc = (tid & 15) ^ (rl & 7);
        async16(xh + (size_t)(m0 + rl) * NF + k0 + sc * 8,
                &As[rl * 128 + (tid & 15) * 8]);
      }
      // B convert -> XOR-swizzled LDS (16 chunks/row, c ^ row&7)
#pragma unroll
      for (int h = 0; h < 4; ++h) {
        half8 hh;
        hh[0] = (_Float16)fv[2 * h].x; hh[1] = (_Float16)fv[2 * h].y;
        hh[2] = (_Float16)fv[2 * h].z; hh[3] = (_Float16)fv[2 * h].w;
        hh[4] = (_Float16)fv[2 * h + 1].x; hh[5] = (_Float16)fv[2 * h + 1].y;
        hh[6] = (_Float16)fv[2 * h + 1].z; hh[7] = (_Float16)fv[2 * h + 1].w;
        int c = bq * 4 + h;
        *(half8*)&Bs[brow * 128 + ((c ^ (brow & 7)) << 3)] = hh;
      }
      __syncthreads();  // (b) drains async16 (L2) + ds_writes only
      // outF store after (b): ack drains at next (a), covered by MFMA phase.
      if (by == (k0 >= NF / 2 ? 1 : 0)) {
        float4* o = (float4*)(outF + (size_t)(n0 + brow) * NF + k0 + bq * 32);
#pragma unroll
        for (int q = 0; q < 8; ++q) o[q] = fv[q];
      }
      // issue next fv during MFMA phase: HBM latency hidden under compute
      if (k0 + 128 < NF) {
#pragma unroll
        for (int q = 0; q < 8; ++q)
          fv[q] = *(const float4*)(bsrc + k0 + 128 + q * 4);
      }
      // MFMA on the staged tile (4 k-subs)
#pragma unroll
      for (int sub = 0; sub < 4; ++sub) {
        int slot = ((sub * 4 + quad) ^ (r16 & 7)) * 8;
        half8 af[2], bf[4];
#pragma unroll
        for (int i = 0; i < 2; ++i)
          af[i] = *(const half8*)&As[(wave * 32 + i * 16 + r16) * 128 + slot];
#pragma unroll
        for (int j = 0; j < 4; ++j)
          bf[j] = *(const half8*)&Bs[(j * 16 + r16) * 128 + slot];
#pragma unroll
        for (int i = 0; i < 2; ++i)
#pragma unroll
          for (int j = 0; j < 4; ++j)
            acc[i][j] = __builtin_amdgcn_mfma_f32_16x16x32_f16(af[i], bf[j], acc[i][j], 0, 0, 0);
      }
    }
    // epilogue: per-row LSE over this block's 64 cols -> stripe bx
#pragma unroll
    for (int i = 0; i < 2; ++i)
#pragma unroll
      for (int r = 0; r < 4; ++r) {
        int R = m0 + wave * 32 + i * 16 + quad * 4 + r;
        float sv[4];
#pragma unroll
        for (int j = 0; j < 4; ++j) sv[j] = acc[i][j][r] * 20.0f;  // 1/TEMP
        float mx = fmaxf(fmaxf(sv[0], sv[1]), fmaxf(sv[2], sv[3]));
#pragma unroll
        for (int m2 = 1; m2 < 16; m2 <<= 1) mx = fmaxf(mx, __shfl_xor(mx, m2, 64));
        float e = expf(sv[0] - mx) + expf(sv[1] - mx) + expf(sv[2] - mx) + expf(sv[3] - mx);
#pragma unroll
        for (int m2 = 1; m2 < 16; m2 <<= 1) e += __shfl_xor(e, m2, 64);
        int tg = targets[R];
#pragma unroll
        for (int j = 0; j < 4; ++j)
          if (n0 + j * 16 + r16 == tg) tgt[R] = sv[j];
        if (r16 == 0) { pm[R * 128 + bx] = mx; pl[R * 128 + bx] = e; }
      }
  } else {
    // ---- sparse neighbor-gather CE/KL ----
    int gb = blk - 256;
    int b = gb >> 2, s0 = (gb & 3) * 2048;
    float s = 0.0f;
    int cnt = 0;
#pragma unroll
    for (int k = 0; k < NK; ++k) {
      float d = ndist[b * NK + k];
      s += expf(d * (1.0f / 0.6f));
      cnt += (d <= 2.0f) ? 1 : 0;
    }
    float invs = 1.0f / (2.0f * s);
    float invc = 1.0f / fmaxf((float)cnt, 1.0f);
    float ce[8] = {0, 0, 0, 0, 0, 0, 0, 0};
    float kl[8] = {0, 0, 0, 0, 0, 0, 0, 0};
    int sc_ = s0 + tid * 8;
#pragma unroll 4
    for (int k = 0; k < NK; ++k) {
      float d = ndist[b * NK + k];
      int n = neighbors[b * NK + k];
      float wce = expf(d * (1.0f / 0.6f)) * invs;
      float wkl = (d <= 2.0f) ? invc : 0.0f;
      float a0 = alpha[n], a1 = alpha[256 + n];
      float c0 = wce * a0, c1 = wce * a1, ck = wkl * a0;
      half8 p0 = *(const half8*)(P + (size_t)n * NS + sc_);
      half8 p1 = *(const half8*)(P + (size_t)(256 + n) * NS + sc_);
#pragma unroll
      for (int e2 = 0; e2 < 8; ++e2) {
        float q0 = (float)p0[e2], q1 = (float)p1[e2];
        ce[e2] += c0 * q0 + c1 * q1;
        kl[e2] += ck * q0;
      }
    }
    float mv0 = mll[b], mv1 = mll[256 + b];
    const float* g0 = logits0 + (size_t)b * NS + sc_;
    const float* g1 = logits1 + (size_t)b * NS + sc_;
    float4 l0a = *(const float4*)g0, l0b = *(const float4*)(g0 + 4);
    float4 l1a = *(const float4*)g1, l1b = *(const float4*)(g1 + 4);
    float lg0[8] = {l0a.x, l0a.y, l0a.z, l0a.w, l0b.x, l0b.y, l0b.z, l0b.w};
    float lg1[8] = {l1a.x, l1a.y, l1a.z, l1a.w, l1b.x, l1b.y, l1b.z, l1b.w};
    float lce = 0.0f, lkl = 0.0f;
#pragma unroll
    for (int e2 = 0; e2 < 8; ++e2) {
      float t = ce[e2] * (1.0f / 256.0f);
      lce += t * (lg0[e2] - mv0);
      float tk = kl[e2] * (1.0f / 256.0f);
      lkl += (tk > 0.0f) ? tk * (logf(fmaxf(tk, 1e-12f)) - (lg1[e2] - mv1)) : 0.0f;
    }
    float wc = waveSum(lce), wk = waveSum(lkl);
    if (lane == 0) { red[wave] = wc; red[4 + wave] = wk; }
    __syncthreads();
    if (tid == 0) {
      float ce_t = (red[0] + red[1]) + (red[2] + red[3]);
      float kl_t = (red[4] + red[5]) + (red[6] + red[7]);
      atomicAdd(out + 1, -0.1f * ce_t * (1.0f / 256.0f));
      atomicAdd(out + 2, rampup[0] * kl_t * (1.0f / 256.0f));
    }
  }
}

// ============ K3: finalize + momentum winner rows ============
__global__ __launch_bounds__(128) void final_reduce(
    const float* __restrict__ pm, const float* __restrict__ pl,
    const float* __restrict__ tgt, const float* __restrict__ logits0,
    const float* __restrict__ mll, const int* __restrict__ targets,
    const float* __restrict__ in0, const float* __restrict__ features,
    float* __restrict__ outF, float* __restrict__ out) {
  __shared__ float rA[2], rB[2];
  __shared__ int flag;
  int tid = threadIdx.x, blk = blockIdx.x;
  if (blk < 256) {
    int b = blk;
    float m = pm[b * 128 + tid];
    float l = pl[b * 128 + tid];
    float wm = waveMax(m);
    if ((tid & 63) == 0) rA[tid >> 6] = wm;
    __syncthreads();
    float mx = fmaxf(rA[0], rA[1]);
    float e = l * expf(m - mx);
    float ws = waveSum(e);
    if ((tid & 63) == 0) rB[tid >> 6] = ws;
    __syncthreads();
    if (tid == 0) {
      float S = rB[0] + rB[1];
      float nce = -(tgt[b] - mx - logf(S));
      int tg = targets[b];
      float oh = -0.9f * (logits0[(size_t)b * NS + tg] - mll[b]);
      atomicAdd(out + 0, nce * (1.0f / 256.0f));
      atomicAdd(out + 1, oh * (1.0f / 256.0f));
    }
  } else {
    int b = blk - 256;
    int tg = targets[b];
    if (tid == 0) flag = 0;
    __syncthreads();
    bool later = false;
    for (int i = b + 1 + tid; i < 256; i += 128) later = later || (targets[i] == tg);
    if (later) flag = 1;
    __syncthreads();
    if (flag) return;  // some later batch row owns this target
    const float4* xr = (const float4*)(in0 + (size_t)b * NF);
    const float4* fr = (const float4*)(features + (size_t)tg * NF);
    float4 a[4];
    float ssx = 0.0f;
#pragma unroll
    for (int s = 0; s < 4; ++s) {
      a[s] = xr[tid + s * 128];
      ssx += a[s].x * a[s].x + a[s].y * a[s].y + a[s].z * a[s].z + a[s].w * a[s].w;
    }
    float w1 = waveSum(ssx);
    if ((tid & 63) == 0) rA[tid >> 6] = w1;
    __syncthreads();
    float ix = 0.8f / fmaxf(sqrtf(rA[0] + rA[1]), 1e-12f);
    float4 v[4];
    float ss = 0.0f;
#pragma unroll
    for (int s = 0; s < 4; ++s) {
      float4 f = fr[tid + s * 128];
      v[s] = make_float4(0.2f * f.x + ix * a[s].x, 0.2f * f.y + ix * a[s].y,
                         0.2f * f.z + ix * a[s].z, 0.2f * f.w + ix * a[s].w);
      ss += v[s].x * v[s].x + v[s].y * v[s].y + v[s].z * v[s].z + v[s].w * v[s].w;
    }
    float w2 = waveSum(ss);
    if ((tid & 63) == 0) rB[tid >> 6] = w2;
    __syncthreads();
    float inv = 1.0f / fmaxf(sqrtf(rB[0] + rB[1]), 1e-12f);
    float4* o4 = (float4*)(outF + (size_t)tg * NF);
#pragma unroll
    for (int s = 0; s < 4; ++s)
      o4[tid + s * 128] = make_float4(v[s].x * inv, v[s].y * inv, v[s].z * inv, v[s].w * inv);
  }
}

extern "C" void kernel_launch(void* const* d_in, const int* in_sizes, int n_in,
                              void* d_out, int out_size, void* d_ws, size_t ws_size,
                              hipStream_t stream) {
  const float* inputs0 = (const float*)d_in[0];
  const float* logits0 = (const float*)d_in[1];
  const float* logits1 = (const float*)d_in[2];
  const int* targets = (const int*)d_in[3];
  const int* neighbors = (const int*)d_in[5];
  const float* ndist = (const float*)d_in[6];
  const float* rampup = (const float*)d_in[7];
  const float* features = (const float*)d_in[8];
  float* out = (float*)d_out;

  char* ws = (char*)d_ws;
  float* mll = (float*)(ws + 4096);            // 2 KB
  float* alpha = (float*)(ws + 8192);          // 2 KB (f32)
  float* tgt = (float*)(ws + 16384);           // 1 KB
  float* pm = (float*)(ws + 65536);            // 128 KB (256 rows x 128 stripes)
  float* pl = (float*)(ws + 196608);           // 128 KB
  _Float16* xh = (_Float16*)(ws + (3 << 20));  // 1 MB
  _Float16* P = (_Float16*)(ws + (4 << 20));   // 8 MB (row-major raw exp)

  prep<<<768, 256, 0, stream>>>(inputs0, logits0, logits1, P, xh, alpha, mll, out);
  fused2<<<1280, 256, 0, stream>>>(xh, features, P, alpha, mll, logits0, logits1,
                                   targets, neighbors, ndist, rampup, out + 3,
                                   pm, pl, tgt, out);
  final_reduce<<<512, 128, 0, stream>>>(pm, pl, tgt, logits0, mll, targets,
                                        inputs0, features, out + 3, out);
}

// Round 9
// 199.498 us; speedup vs baseline: 1.0381x; 1.0275x over previous
//
#include <hip/hip_runtime.h>
#include <cmath>

#define NB 256
#define NS 8192
#define NF 2048
#define NK 20

typedef _Float16 half8 __attribute__((ext_vector_type(8)));
typedef _Float16 half4 __attribute__((ext_vector_type(4)));
typedef float f32x4 __attribute__((ext_vector_type(4)));

__device__ __forceinline__ void async16(const void* g, void* l) {
  __builtin_amdgcn_global_load_lds(
      (const __attribute__((address_space(1))) unsigned int*)g,
      (__attribute__((address_space(3))) unsigned int*)l, 16, 0, 0);
}

__device__ __forceinline__ float waveSum(float v) {
#pragma unroll
  for (int off = 32; off > 0; off >>= 1) v += __shfl_xor(v, off, 64);
  return v;
}
__device__ __forceinline__ float waveMax(float v) {
#pragma unroll
  for (int off = 32; off > 0; off >>= 1) v = fmaxf(v, __shfl_xor(v, off, 64));
  return v;
}

// ============ K1: prep ============
// blocks [0,512): FUSED row stats + raw-exp P write (one logits pass).
// blocks [512,768): normalize x -> xh fp16.
__global__ __launch_bounds__(256) void prep(
    const float* __restrict__ in0, const float* __restrict__ logits0,
    const float* __restrict__ logits1, _Float16* __restrict__ P,
    _Float16* __restrict__ xh, float* __restrict__ alpha,
    float* __restrict__ mll, float* __restrict__ loss) {
  __shared__ float redA[4], redB[4];
  int tid = threadIdx.x, blk = blockIdx.x;
  int wave = tid >> 6, lane = tid & 63;

  if (blk < 512) {
    if (blk == 0 && tid < 3) loss[tid] = 0.0f;  // zero loss accumulators
    int r = blk;
    const float* src = (r < NB) ? logits0 : logits1;
    const float4* row = (const float4*)(src + (size_t)(r & (NB - 1)) * NS);
    float4 v[8];
    float mx = -1e30f;
#pragma unroll
    for (int i = 0; i < 8; ++i) {
      v[i] = row[tid + i * 256];
      mx = fmaxf(mx, fmaxf(fmaxf(v[i].x, v[i].y), fmaxf(v[i].z, v[i].w)));
    }
    float wv = waveMax(mx);
    if (lane == 0) redA[wave] = wv;
    __syncthreads();
    float m = fmaxf(fmaxf(redA[0], redA[1]), fmaxf(redA[2], redA[3]));
    float em = expf(m);
    float se = 0.0f;
    half4* prow = (half4*)(P + (size_t)r * NS);
#pragma unroll
    for (int i = 0; i < 8; ++i) {
      float e0 = expf(v[i].x - m), e1 = expf(v[i].y - m);
      float e2 = expf(v[i].z - m), e3 = expf(v[i].w - m);
      se += (e0 + e1) + (e2 + e3);
      half4 h;
      h[0] = (_Float16)(e0 * em); h[1] = (_Float16)(e1 * em);
      h[2] = (_Float16)(e2 * em); h[3] = (_Float16)(e3 * em);
      prow[tid + i * 256] = h;
    }
    float sw = waveSum(se);
    if (lane == 0) redB[wave] = sw;
    __syncthreads();
    float l = (redB[0] + redB[1]) + (redB[2] + redB[3]);
    if (tid == 0) {
      mll[r] = m + logf(l);
      alpha[r] = 256.0f * expf(-m) / l;
    }
  } else {
    // ---- normalize x -> xh ----
    int b = blk - 512;
    const float4* row = (const float4*)(in0 + (size_t)b * NF);
    float4 v0 = row[tid], v1 = row[tid + 256];
    float ss = v0.x * v0.x + v0.y * v0.y + v0.z * v0.z + v0.w * v0.w +
               v1.x * v1.x + v1.y * v1.y + v1.z * v1.z + v1.w * v1.w;
    float w = waveSum(ss);
    if (lane == 0) redA[wave] = w;
    __syncthreads();
    float tot = (redA[0] + redA[1]) + (redA[2] + redA[3]);
    float inv = 1.0f / fmaxf(sqrtf(tot), 1e-12f);
    half4 h0, h1;
    h0[0] = (_Float16)(v0.x * inv); h0[1] = (_Float16)(v0.y * inv);
    h0[2] = (_Float16)(v0.z * inv); h0[3] = (_Float16)(v0.w * inv);
    h1[0] = (_Float16)(v1.x * inv); h1[1] = (_Float16)(v1.y * inv);
    h1[2] = (_Float16)(v1.z * inv); h1[3] = (_Float16)(v1.w * inv);
    ((half4*)(xh + (size_t)b * NF))[tid] = h0;
    ((half4*)(xh + (size_t)b * NF))[tid + 256] = h1;
  }
}

// ============ K2: GEMM1 (M=128 x N=32, 512 blocks = 2/CU) + sparse gather ============
// blocks [0,512): scores = x@F^T. BK=64, R6's proven conflict-free swizzles;
//   fv(k+1) issued during MFMA (drain covered at next barrier-a); outF store
//   after barrier-b. XCD-pair swizzle: by-pair of each bx on one XCD.
// blocks [512,1536): gather block (b, s-slice): sparse 20-neighbor weighted
//   sums over P rows, fused CE/KL epilogue, atomicAdd out[1],out[2].
__global__ __launch_bounds__(256) void fused2(
    const _Float16* __restrict__ xh, const float* __restrict__ fB,
    const _Float16* __restrict__ P, const float* __restrict__ alpha,
    const float* __restrict__ mll, const float* __restrict__ logits0,
    const float* __restrict__ logits1, const int* __restrict__ targets,
    const int* __restrict__ neighbors, const float* __restrict__ ndist,
    const float* __restrict__ rampup, float* __restrict__ outF,
    float* __restrict__ pm, float* __restrict__ pl, float* __restrict__ tgt,
    float* __restrict__ out) {
  __shared__ alignas(16) _Float16 As[128 * 64];  // 16 KB
  __shared__ alignas(16) _Float16 Bs[32 * 64];   // 4 KB
  __shared__ float red[8];
  int tid = threadIdx.x, wave = tid >> 6, lane = tid & 63;
  int quad = lane >> 4, r16 = lane & 15;
  int blk = blockIdx.x;

  if (blk < 512) {
    // XCD-pair swizzle: by-pair (blk, blk^8) share the same bx stripe
    int by = (blk >> 3) & 1;
    int bx = (blk & 7) | ((blk >> 4) << 3);
    int n0 = bx * 32, m0 = by * 128;
    int brow = tid >> 3, bq = tid & 7;  // B staging: row(32), 8-float group
    const float* bsrc = fB + (size_t)(n0 + brow) * NF + bq * 8;

    float4 fv[2];
    f32x4 acc[2][2] = {};
    // prologue: issue fv(0); its drain at the first barrier-a is exposed once
    fv[0] = *(const float4*)bsrc;
    fv[1] = *(const float4*)(bsrc + 4);

    for (int k0 = 0; k0 < NF; k0 += 64) {
      __syncthreads();  // (a) prev tile consumed; fv(k0) mostly arrived
      // A tile: 128 rows x 64 cols via async16, pre-swizzled source (R6)
#pragma unroll
      for (int ss = 0; ss < 4; ++ss) {
        int rl = ss * 32 + (tid >> 3);
        int sc = (tid & 7) ^ (rl & 7);
        async16(xh + (size_t)(m0 + rl) * NF + k0 + sc * 8,
                &As[rl * 64 + (tid & 7) * 8]);
      }
      // B convert -> XOR-swizzled LDS: 8 chunks/row, chunk bq ^ (row&7) (R6)
      {
        half8 hh;
        hh[0] = (_Float16)fv[0].x; hh[1] = (_Float16)fv[0].y;
        hh[2] = (_Float16)fv[0].z; hh[3] = (_Float16)fv[0].w;
        hh[4] = (_Float16)fv[1].x; hh[5] = (_Float16)fv[1].y;
        hh[6] = (_Float16)fv[1].z; hh[7] = (_Float16)fv[1].w;
        *(half8*)&Bs[brow * 64 + ((bq ^ (brow & 7)) << 3)] = hh;
      }
      __syncthreads();  // (b) drains async16 (L2-hot) + ds_writes
      // outF store after (b): ack drains at next (a), covered by MFMA + issue
      if (by == (k0 >= NF / 2 ? 1 : 0)) {
        float4* o = (float4*)(outF + (size_t)(n0 + brow) * NF + k0 + bq * 8);
        o[0] = fv[0];
        o[1] = fv[1];
      }
      // issue next fv during MFMA phase: HBM latency mostly hidden
      if (k0 + 64 < NF) {
        fv[0] = *(const float4*)(bsrc + k0 + 64);
        fv[1] = *(const float4*)(bsrc + k0 + 68);
      }
      // MFMA on staged tile
#pragma unroll
      for (int sub = 0; sub < 2; ++sub) {
        int slot = ((sub * 4 + quad) ^ (r16 & 7)) * 8;
        half8 af[2], bf[2];
#pragma unroll
        for (int i = 0; i < 2; ++i)
          af[i] = *(const half8*)&As[(wave * 32 + i * 16 + r16) * 64 + slot];
#pragma unroll
        for (int j = 0; j < 2; ++j)
          bf[j] = *(const half8*)&Bs[(j * 16 + r16) * 64 + slot];
#pragma unroll
        for (int i = 0; i < 2; ++i)
#pragma unroll
          for (int j = 0; j < 2; ++j)
            acc[i][j] = __builtin_amdgcn_mfma_f32_16x16x32_f16(af[i], bf[j], acc[i][j], 0, 0, 0);
      }
    }
    // epilogue: per-row LSE over this block's 32 cols -> stripe bx (of 256)
#pragma unroll
    for (int i = 0; i < 2; ++i)
#pragma unroll
      for (int r = 0; r < 4; ++r) {
        int R = m0 + wave * 32 + i * 16 + quad * 4 + r;
        float s0 = acc[i][0][r] * 20.0f, s1 = acc[i][1][r] * 20.0f;  // 1/TEMP
        float mx = fmaxf(s0, s1);
#pragma unroll
        for (int m2 = 1; m2 < 16; m2 <<= 1) mx = fmaxf(mx, __shfl_xor(mx, m2, 64));
        float e = expf(s0 - mx) + expf(s1 - mx);
#pragma unroll
        for (int m2 = 1; m2 < 16; m2 <<= 1) e += __shfl_xor(e, m2, 64);
        int tg = targets[R];
        if (n0 + r16 == tg) tgt[R] = s0;
        if (n0 + 16 + r16 == tg) tgt[R] = s1;
        if (r16 == 0) { pm[R * 256 + bx] = mx; pl[R * 256 + bx] = e; }
      }
  } else {
    // ---- sparse neighbor-gather CE/KL ----
    int gb = blk - 512;
    int b = gb >> 2, s0 = (gb & 3) * 2048;
    float s = 0.0f;
    int cnt = 0;
#pragma unroll
    for (int k = 0; k < NK; ++k) {
      float d = ndist[b * NK + k];
      s += expf(d * (1.0f / 0.6f));
      cnt += (d <= 2.0f) ? 1 : 0;
    }
    float invs = 1.0f / (2.0f * s);
    float invc = 1.0f / fmaxf((float)cnt, 1.0f);
    float ce[8] = {0, 0, 0, 0, 0, 0, 0, 0};
    float kl[8] = {0, 0, 0, 0, 0, 0, 0, 0};
    int sc_ = s0 + tid * 8;
#pragma unroll 4
    for (int k = 0; k < NK; ++k) {
      float d = ndist[b * NK + k];
      int n = neighbors[b * NK + k];
      float wce = expf(d * (1.0f / 0.6f)) * invs;
      float wkl = (d <= 2.0f) ? invc : 0.0f;
      float a0 = alpha[n], a1 = alpha[256 + n];
      float c0 = wce * a0, c1 = wce * a1, ck = wkl * a0;
      half8 p0 = *(const half8*)(P + (size_t)n * NS + sc_);
      half8 p1 = *(const half8*)(P + (size_t)(256 + n) * NS + sc_);
#pragma unroll
      for (int e2 = 0; e2 < 8; ++e2) {
        float q0 = (float)p0[e2], q1 = (float)p1[e2];
        ce[e2] += c0 * q0 + c1 * q1;
        kl[e2] += ck * q0;
      }
    }
    float mv0 = mll[b], mv1 = mll[256 + b];
    const float* g0 = logits0 + (size_t)b * NS + sc_;
    const float* g1 = logits1 + (size_t)b * NS + sc_;
    float4 l0a = *(const float4*)g0, l0b = *(const float4*)(g0 + 4);
    float4 l1a = *(const float4*)g1, l1b = *(const float4*)(g1 + 4);
    float lg0[8] = {l0a.x, l0a.y, l0a.z, l0a.w, l0b.x, l0b.y, l0b.z, l0b.w};
    float lg1[8] = {l1a.x, l1a.y, l1a.z, l1a.w, l1b.x, l1b.y, l1b.z, l1b.w};
    float lce = 0.0f, lkl = 0.0f;
#pragma unroll
    for (int e2 = 0; e2 < 8; ++e2) {
      float t = ce[e2] * (1.0f / 256.0f);
      lce += t * (lg0[e2] - mv0);
      float tk = kl[e2] * (1.0f / 256.0f);
      lkl += (tk > 0.0f) ? tk * (logf(fmaxf(tk, 1e-12f)) - (lg1[e2] - mv1)) : 0.0f;
    }
    float wc = waveSum(lce), wk = waveSum(lkl);
    if (lane == 0) { red[wave] = wc; red[4 + wave] = wk; }
    __syncthreads();
    if (tid == 0) {
      float ce_t = (red[0] + red[1]) + (red[2] + red[3]);
      float kl_t = (red[4] + red[5]) + (red[6] + red[7]);
      atomicAdd(out + 1, -0.1f * ce_t * (1.0f / 256.0f));
      atomicAdd(out + 2, rampup[0] * kl_t * (1.0f / 256.0f));
    }
  }
}

// ============ K3: finalize + momentum winner rows ============
// blocks [0,256): LSE over 256 stripes of row b + CE-onehot -> atomics
// blocks [256,512): momentum winner rows overwrite outF[targets[b]].
__global__ __launch_bounds__(128) void final_reduce(
    const float* __restrict__ pm, const float* __restrict__ pl,
    const float* __restrict__ tgt, const float* __restrict__ logits0,
    const float* __restrict__ mll, const int* __restrict__ targets,
    const float* __restrict__ in0, const float* __restrict__ features,
    float* __restrict__ outF, float* __restrict__ out) {
  __shared__ float rA[2], rB[2];
  __shared__ int flag;
  int tid = threadIdx.x, blk = blockIdx.x;
  if (blk < 256) {
    int b = blk;
    float m1 = pm[b * 256 + tid], m2v = pm[b * 256 + 128 + tid];
    float l1 = pl[b * 256 + tid], l2v = pl[b * 256 + 128 + tid];
    float wm = waveMax(fmaxf(m1, m2v));
    if ((tid & 63) == 0) rA[tid >> 6] = wm;
    __syncthreads();
    float mx = fmaxf(rA[0], rA[1]);
    float e = l1 * expf(m1 - mx) + l2v * expf(m2v - mx);
    float ws = waveSum(e);
    if ((tid & 63) == 0) rB[tid >> 6] = ws;
    __syncthreads();
    if (tid == 0) {
      float S = rB[0] + rB[1];
      float nce = -(tgt[b] - mx - logf(S));
      int tg = targets[b];
      float oh = -0.9f * (logits0[(size_t)b * NS + tg] - mll[b]);
      atomicAdd(out + 0, nce * (1.0f / 256.0f));
      atomicAdd(out + 1, oh * (1.0f / 256.0f));
    }
  } else {
    int b = blk - 256;
    int tg = targets[b];
    if (tid == 0) flag = 0;
    __syncthreads();
    bool later = false;
    for (int i = b + 1 + tid; i < 256; i += 128) later = later || (targets[i] == tg);
    if (later) flag = 1;
    __syncthreads();
    if (flag) return;  // some later batch row owns this target
    const float4* xr = (const float4*)(in0 + (size_t)b * NF);
    const float4* fr = (const float4*)(features + (size_t)tg * NF);
    float4 a[4];
    float ssx = 0.0f;
#pragma unroll
    for (int s = 0; s < 4; ++s) {
      a[s] = xr[tid + s * 128];
      ssx += a[s].x * a[s].x + a[s].y * a[s].y + a[s].z * a[s].z + a[s].w * a[s].w;
    }
    float w1 = waveSum(ssx);
    if ((tid & 63) == 0) rA[tid >> 6] = w1;
    __syncthreads();
    float ix = 0.8f / fmaxf(sqrtf(rA[0] + rA[1]), 1e-12f);
    float4 v[4];
    float ss = 0.0f;
#pragma unroll
    for (int s = 0; s < 4; ++s) {
      float4 f = fr[tid + s * 128];
      v[s] = make_float4(0.2f * f.x + ix * a[s].x, 0.2f * f.y + ix * a[s].y,
                         0.2f * f.z + ix * a[s].z, 0.2f * f.w + ix * a[s].w);
      ss += v[s].x * v[s].x + v[s].y * v[s].y + v[s].z * v[s].z + v[s].w * v[s].w;
    }
    float w2 = waveSum(ss);
    if ((tid & 63) == 0) rB[tid >> 6] = w2;
    __syncthreads();
    float inv = 1.0f / fmaxf(sqrtf(rB[0] + rB[1]), 1e-12f);
    float4* o4 = (float4*)(outF + (size_t)tg * NF);
#pragma unroll
    for (int s = 0; s < 4; ++s)
      o4[tid + s * 128] = make_float4(v[s].x * inv, v[s].y * inv, v[s].z * inv, v[s].w * inv);
  }
}

extern "C" void kernel_launch(void* const* d_in, const int* in_sizes, int n_in,
                              void* d_out, int out_size, void* d_ws, size_t ws_size,
                              hipStream_t stream) {
  const float* inputs0 = (const float*)d_in[0];
  const float* logits0 = (const float*)d_in[1];
  const float* logits1 = (const float*)d_in[2];
  const int* targets = (const int*)d_in[3];
  const int* neighbors = (const int*)d_in[5];
  const float* ndist = (const float*)d_in[6];
  const float* rampup = (const float*)d_in[7];
  const float* features = (const float*)d_in[8];
  float* out = (float*)d_out;

  char* ws = (char*)d_ws;
  float* mll = (float*)(ws + 4096);            // 2 KB
  float* alpha = (float*)(ws + 8192);          // 2 KB (f32)
  float* tgt = (float*)(ws + 16384);           // 1 KB
  float* pm = (float*)(ws + 65536);            // 256 KB (256 rows x 256 stripes)
  float* pl = (float*)(ws + 65536 + 262144);   // 256 KB
  _Float16* xh = (_Float16*)(ws + (3 << 20));  // 1 MB
  _Float16* P = (_Float16*)(ws + (4 << 20));   // 8 MB (row-major raw exp)

  prep<<<768, 256, 0, stream>>>(inputs0, logits0, logits1, P, xh, alpha, mll, out);
  fused2<<<1536, 256, 0, stream>>>(xh, features, P, alpha, mll, logits0, logits1,
                                   targets, neighbors, ndist, rampup, out + 3,
                                   pm, pl, tgt, out);
  final_reduce<<<512, 128, 0, stream>>>(pm, pl, tgt, logits0, mll, targets,
                                        inputs0, features, out + 3, out);
}

// Round 10
// 199.020 us; speedup vs baseline: 1.0406x; 1.0024x over previous
//
#include <hip/hip_runtime.h>
#include <cmath>

#define NB 256
#define NS 8192
#define NF 2048
#define NK 20

typedef _Float16 half8 __attribute__((ext_vector_type(8)));
typedef _Float16 half4 __attribute__((ext_vector_type(4)));
typedef float f32x4 __attribute__((ext_vector_type(4)));

__device__ __forceinline__ void async16(const void* g, void* l) {
  __builtin_amdgcn_global_load_lds(
      (const __attribute__((address_space(1))) unsigned int*)g,
      (__attribute__((address_space(3))) unsigned int*)l, 16, 0, 0);
}

__device__ __forceinline__ float waveSum(float v) {
#pragma unroll
  for (int off = 32; off > 0; off >>= 1) v += __shfl_xor(v, off, 64);
  return v;
}
__device__ __forceinline__ float waveMax(float v) {
#pragma unroll
  for (int off = 32; off > 0; off >>= 1) v = fmaxf(v, __shfl_xor(v, off, 64));
  return v;
}

// ============ K1: prep ============
// blocks [0,512): FUSED row stats + raw-exp P write (one logits pass).
// blocks [512,768): normalize x -> xh fp16.
__global__ __launch_bounds__(256) void prep(
    const float* __restrict__ in0, const float* __restrict__ logits0,
    const float* __restrict__ logits1, _Float16* __restrict__ P,
    _Float16* __restrict__ xh, float* __restrict__ alpha,
    float* __restrict__ mll, float* __restrict__ loss) {
  __shared__ float redA[4], redB[4];
  int tid = threadIdx.x, blk = blockIdx.x;
  int wave = tid >> 6, lane = tid & 63;

  if (blk < 512) {
    if (blk == 0 && tid < 3) loss[tid] = 0.0f;  // zero loss accumulators
    int r = blk;
    const float* src = (r < NB) ? logits0 : logits1;
    const float4* row = (const float4*)(src + (size_t)(r & (NB - 1)) * NS);
    float4 v[8];
    float mx = -1e30f;
#pragma unroll
    for (int i = 0; i < 8; ++i) {
      v[i] = row[tid + i * 256];
      mx = fmaxf(mx, fmaxf(fmaxf(v[i].x, v[i].y), fmaxf(v[i].z, v[i].w)));
    }
    float wv = waveMax(mx);
    if (lane == 0) redA[wave] = wv;
    __syncthreads();
    float m = fmaxf(fmaxf(redA[0], redA[1]), fmaxf(redA[2], redA[3]));
    float em = expf(m);
    float se = 0.0f;
    half4* prow = (half4*)(P + (size_t)r * NS);
#pragma unroll
    for (int i = 0; i < 8; ++i) {
      float e0 = expf(v[i].x - m), e1 = expf(v[i].y - m);
      float e2 = expf(v[i].z - m), e3 = expf(v[i].w - m);
      se += (e0 + e1) + (e2 + e3);
      half4 h;
      h[0] = (_Float16)(e0 * em); h[1] = (_Float16)(e1 * em);
      h[2] = (_Float16)(e2 * em); h[3] = (_Float16)(e3 * em);
      prow[tid + i * 256] = h;
    }
    float sw = waveSum(se);
    if (lane == 0) redB[wave] = sw;
    __syncthreads();
    float l = (redB[0] + redB[1]) + (redB[2] + redB[3]);
    if (tid == 0) {
      mll[r] = m + logf(l);
      alpha[r] = 256.0f * expf(-m) / l;
    }
  } else {
    // ---- normalize x -> xh ----
    int b = blk - 512;
    const float4* row = (const float4*)(in0 + (size_t)b * NF);
    float4 v0 = row[tid], v1 = row[tid + 256];
    float ss = v0.x * v0.x + v0.y * v0.y + v0.z * v0.z + v0.w * v0.w +
               v1.x * v1.x + v1.y * v1.y + v1.z * v1.z + v1.w * v1.w;
    float w = waveSum(ss);
    if (lane == 0) redA[wave] = w;
    __syncthreads();
    float tot = (redA[0] + redA[1]) + (redA[2] + redA[3]);
    float inv = 1.0f / fmaxf(sqrtf(tot), 1e-12f);
    half4 h0, h1;
    h0[0] = (_Float16)(v0.x * inv); h0[1] = (_Float16)(v0.y * inv);
    h0[2] = (_Float16)(v0.z * inv); h0[3] = (_Float16)(v0.w * inv);
    h1[0] = (_Float16)(v1.x * inv); h1[1] = (_Float16)(v1.y * inv);
    h1[2] = (_Float16)(v1.z * inv); h1[3] = (_Float16)(v1.w * inv);
    ((half4*)(xh + (size_t)b * NF))[tid] = h0;
    ((half4*)(xh + (size_t)b * NF))[tid + 256] = h1;
  }
}

// ============ K2: GEMM1 (counted-vmcnt loop) + copy + sparse gather ============
// blocks [0,512): scores = x@F^T. M=128 x N=32, BK=64. Raw s_barrier + counted
//   s_waitcnt vmcnt(2): waits only the 4 async16 A-loads; the 2 fv feature
//   loads stay in flight across the barrier (consumed next iter). No stores
//   inside the loop (no store-ack drains). R6/R9 conflict-free swizzles.
// blocks [512,1536): gather block: FIRST copy 8 features rows -> outF
//   (features L3-hot from GEMM streams), then sparse 20-neighbor CE/KL sums
//   over P rows, fused epilogue, atomicAdd out[1],out[2].
__global__ __launch_bounds__(256) void fused2(
    const _Float16* __restrict__ xh, const float* __restrict__ fB,
    const _Float16* __restrict__ P, const float* __restrict__ alpha,
    const float* __restrict__ mll, const float* __restrict__ logits0,
    const float* __restrict__ logits1, const int* __restrict__ targets,
    const int* __restrict__ neighbors, const float* __restrict__ ndist,
    const float* __restrict__ rampup, float* __restrict__ outF,
    float* __restrict__ pm, float* __restrict__ pl, float* __restrict__ tgt,
    float* __restrict__ out) {
  __shared__ alignas(16) _Float16 As[128 * 64];  // 16 KB
  __shared__ alignas(16) _Float16 Bs[32 * 64];   // 4 KB
  __shared__ float red[8];
  int tid = threadIdx.x, wave = tid >> 6, lane = tid & 63;
  int quad = lane >> 4, r16 = lane & 15;
  int blk = blockIdx.x;

  if (blk < 512) {
    // XCD-pair swizzle: by-pair (blk, blk^8) share the same bx stripe
    int by = (blk >> 3) & 1;
    int bx = (blk & 7) | ((blk >> 4) << 3);
    int n0 = bx * 32, m0 = by * 128;
    int brow = tid >> 3, bq = tid & 7;  // B staging: row(32), 8-float group
    const float* bsrc = fB + (size_t)(n0 + brow) * NF + bq * 8;

    float4 fv[2];
    f32x4 acc[2][2] = {};
    // prologue: fv(0) in flight; consumed by first ds_write (auto-wait)
    fv[0] = *(const float4*)bsrc;
    fv[1] = *(const float4*)(bsrc + 4);

    for (int k0 = 0; k0 < NF; k0 += 64) {
      __builtin_amdgcn_s_barrier();  // top: all waves' LDS reads consumed
      // A tile: 4 x async16 (oldest vmem ops this iter)
#pragma unroll
      for (int ss = 0; ss < 4; ++ss) {
        int rl = ss * 32 + (tid >> 3);
        int sc = (tid & 7) ^ (rl & 7);
        async16(xh + (size_t)(m0 + rl) * NF + k0 + sc * 8,
                &As[rl * 64 + (tid & 7) * 8]);
      }
      __builtin_amdgcn_sched_barrier(0);  // pin: async16 issued before fv
      // B convert+write (auto-wait retires fv(k) only: vmcnt(4))
      {
        half8 hh;
        hh[0] = (_Float16)fv[0].x; hh[1] = (_Float16)fv[0].y;
        hh[2] = (_Float16)fv[0].z; hh[3] = (_Float16)fv[0].w;
        hh[4] = (_Float16)fv[1].x; hh[5] = (_Float16)fv[1].y;
        hh[6] = (_Float16)fv[1].z; hh[7] = (_Float16)fv[1].w;
        *(half8*)&Bs[brow * 64 + ((bq ^ (brow & 7)) << 3)] = hh;
      }
      if (k0 + 64 < NF) {
        // fv(k+1): newest vmem; stays in flight across the barrier
        fv[0] = *(const float4*)(bsrc + k0 + 64);
        fv[1] = *(const float4*)(bsrc + k0 + 68);
        __builtin_amdgcn_sched_barrier(0);
        asm volatile("s_waitcnt vmcnt(2) lgkmcnt(0)");  // async16+ds_write done
      } else {
        __builtin_amdgcn_sched_barrier(0);
        asm volatile("s_waitcnt vmcnt(0) lgkmcnt(0)");
      }
      __builtin_amdgcn_sched_barrier(0);  // fence: nothing crosses the wait
      __builtin_amdgcn_s_barrier();       // tile ready for all waves
      // MFMA on staged tile
#pragma unroll
      for (int sub = 0; sub < 2; ++sub) {
        int slot = ((sub * 4 + quad) ^ (r16 & 7)) * 8;
        half8 af[2], bf[2];
#pragma unroll
        for (int i = 0; i < 2; ++i)
          af[i] = *(const half8*)&As[(wave * 32 + i * 16 + r16) * 64 + slot];
#pragma unroll
        for (int j = 0; j < 2; ++j)
          bf[j] = *(const half8*)&Bs[(j * 16 + r16) * 64 + slot];
#pragma unroll
        for (int i = 0; i < 2; ++i)
#pragma unroll
          for (int j = 0; j < 2; ++j)
            acc[i][j] = __builtin_amdgcn_mfma_f32_16x16x32_f16(af[i], bf[j], acc[i][j], 0, 0, 0);
      }
    }
    // epilogue: per-row LSE over this block's 32 cols -> stripe bx (of 256)
#pragma unroll
    for (int i = 0; i < 2; ++i)
#pragma unroll
      for (int r = 0; r < 4; ++r) {
        int R = m0 + wave * 32 + i * 16 + quad * 4 + r;
        float s0 = acc[i][0][r] * 20.0f, s1 = acc[i][1][r] * 20.0f;  // 1/TEMP
        float mx = fmaxf(s0, s1);
#pragma unroll
        for (int m2 = 1; m2 < 16; m2 <<= 1) mx = fmaxf(mx, __shfl_xor(mx, m2, 64));
        float e = expf(s0 - mx) + expf(s1 - mx);
#pragma unroll
        for (int m2 = 1; m2 < 16; m2 <<= 1) e += __shfl_xor(e, m2, 64);
        int tg = targets[R];
        if (n0 + r16 == tg) tgt[R] = s0;
        if (n0 + 16 + r16 == tg) tgt[R] = s1;
        if (r16 == 0) { pm[R * 256 + bx] = mx; pl[R * 256 + bx] = e; }
      }
  } else {
    // ---- features -> outF copy (8 rows), then sparse gather CE/KL ----
    int gb = blk - 512;
    {
      const float4* src = (const float4*)fB + (size_t)gb * 8 * 512;
      float4* dst = (float4*)outF + (size_t)gb * 8 * 512;
#pragma unroll
      for (int i = 0; i < 16; ++i) dst[tid + i * 256] = src[tid + i * 256];
    }
    int b = gb >> 2, s0 = (gb & 3) * 2048;
    float s = 0.0f;
    int cnt = 0;
#pragma unroll
    for (int k = 0; k < NK; ++k) {
      float d = ndist[b * NK + k];
      s += expf(d * (1.0f / 0.6f));
      cnt += (d <= 2.0f) ? 1 : 0;
    }
    float invs = 1.0f / (2.0f * s);
    float invc = 1.0f / fmaxf((float)cnt, 1.0f);
    float ce[8] = {0, 0, 0, 0, 0, 0, 0, 0};
    float kl[8] = {0, 0, 0, 0, 0, 0, 0, 0};
    int sc_ = s0 + tid * 8;
#pragma unroll 4
    for (int k = 0; k < NK; ++k) {
      float d = ndist[b * NK + k];
      int n = neighbors[b * NK + k];
      float wce = expf(d * (1.0f / 0.6f)) * invs;
      float wkl = (d <= 2.0f) ? invc : 0.0f;
      float a0 = alpha[n], a1 = alpha[256 + n];
      float c0 = wce * a0, c1 = wce * a1, ck = wkl * a0;
      half8 p0 = *(const half8*)(P + (size_t)n * NS + sc_);
      half8 p1 = *(const half8*)(P + (size_t)(256 + n) * NS + sc_);
#pragma unroll
      for (int e2 = 0; e2 < 8; ++e2) {
        float q0 = (float)p0[e2], q1 = (float)p1[e2];
        ce[e2] += c0 * q0 + c1 * q1;
        kl[e2] += ck * q0;
      }
    }
    float mv0 = mll[b], mv1 = mll[256 + b];
    const float* g0 = logits0 + (size_t)b * NS + sc_;
    const float* g1 = logits1 + (size_t)b * NS + sc_;
    float4 l0a = *(const float4*)g0, l0b = *(const float4*)(g0 + 4);
    float4 l1a = *(const float4*)g1, l1b = *(const float4*)(g1 + 4);
    float lg0[8] = {l0a.x, l0a.y, l0a.z, l0a.w, l0b.x, l0b.y, l0b.z, l0b.w};
    float lg1[8] = {l1a.x, l1a.y, l1a.z, l1a.w, l1b.x, l1b.y, l1b.z, l1b.w};
    float lce = 0.0f, lkl = 0.0f;
#pragma unroll
    for (int e2 = 0; e2 < 8; ++e2) {
      float t = ce[e2] * (1.0f / 256.0f);
      lce += t * (lg0[e2] - mv0);
      float tk = kl[e2] * (1.0f / 256.0f);
      lkl += (tk > 0.0f) ? tk * (logf(fmaxf(tk, 1e-12f)) - (lg1[e2] - mv1)) : 0.0f;
    }
    float wc = waveSum(lce), wk = waveSum(lkl);
    if (lane == 0) { red[wave] = wc; red[4 + wave] = wk; }
    __syncthreads();
    if (tid == 0) {
      float ce_t = (red[0] + red[1]) + (red[2] + red[3]);
      float kl_t = (red[4] + red[5]) + (red[6] + red[7]);
      atomicAdd(out + 1, -0.1f * ce_t * (1.0f / 256.0f));
      atomicAdd(out + 2, rampup[0] * kl_t * (1.0f / 256.0f));
    }
  }
}

// ============ K3: finalize + momentum winner rows ============
// blocks [0,256): LSE over 256 stripes of row b + CE-onehot -> atomics
// blocks [256,512): momentum winner rows overwrite outF[targets[b]].
__global__ __launch_bounds__(128) void final_reduce(
    const float* __restrict__ pm, const float* __restrict__ pl,
    const float* __restrict__ tgt, const float* __restrict__ logits0,
    const float* __restrict__ mll, const int* __restrict__ targets,
    const float* __restrict__ in0, const float* __restrict__ features,
    float* __restrict__ outF, float* __restrict__ out) {
  __shared__ float rA[2], rB[2];
  __shared__ int flag;
  int tid = threadIdx.x, blk = blockIdx.x;
  if (blk < 256) {
    int b = blk;
    float m1 = pm[b * 256 + tid], m2v = pm[b * 256 + 128 + tid];
    float l1 = pl[b * 256 + tid], l2v = pl[b * 256 + 128 + tid];
    float wm = waveMax(fmaxf(m1, m2v));
    if ((tid & 63) == 0) rA[tid >> 6] = wm;
    __syncthreads();
    float mx = fmaxf(rA[0], rA[1]);
    float e = l1 * expf(m1 - mx) + l2v * expf(m2v - mx);
    float ws = waveSum(e);
    if ((tid & 63) == 0) rB[tid >> 6] = ws;
    __syncthreads();
    if (tid == 0) {
      float S = rB[0] + rB[1];
      float nce = -(tgt[b] - mx - logf(S));
      int tg = targets[b];
      float oh = -0.9f * (logits0[(size_t)b * NS + tg] - mll[b]);
      atomicAdd(out + 0, nce * (1.0f / 256.0f));
      atomicAdd(out + 1, oh * (1.0f / 256.0f));
    }
  } else {
    int b = blk - 256;
    int tg = targets[b];
    if (tid == 0) flag = 0;
    __syncthreads();
    bool later = false;
    for (int i = b + 1 + tid; i < 256; i += 128) later = later || (targets[i] == tg);
    if (later) flag = 1;
    __syncthreads();
    if (flag) return;  // some later batch row owns this target
    const float4* xr = (const float4*)(in0 + (size_t)b * NF);
    const float4* fr = (const float4*)(features + (size_t)tg * NF);
    float4 a[4];
    float ssx = 0.0f;
#pragma unroll
    for (int s = 0; s < 4; ++s) {
      a[s] = xr[tid + s * 128];
      ssx += a[s].x * a[s].x + a[s].y * a[s].y + a[s].z * a[s].z + a[s].w * a[s].w;
    }
    float w1 = waveSum(ssx);
    if ((tid & 63) == 0) rA[tid >> 6] = w1;
    __syncthreads();
    float ix = 0.8f / fmaxf(sqrtf(rA[0] + rA[1]), 1e-12f);
    float4 v[4];
    float ss = 0.0f;
#pragma unroll
    for (int s = 0; s < 4; ++s) {
      float4 f = fr[tid + s * 128];
      v[s] = make_float4(0.2f * f.x + ix * a[s].x, 0.2f * f.y + ix * a[s].y,
                         0.2f * f.z + ix * a[s].z, 0.2f * f.w + ix * a[s].w);
      ss += v[s].x * v[s].x + v[s].y * v[s].y + v[s].z * v[s].z + v[s].w * v[s].w;
    }
    float w2 = waveSum(ss);
    if ((tid & 63) == 0) rB[tid >> 6] = w2;
    __syncthreads();
    float inv = 1.0f / fmaxf(sqrtf(rB[0] + rB[1]), 1e-12f);
    float4* o4 = (float4*)(outF + (size_t)tg * NF);
#pragma unroll
    for (int s = 0; s < 4; ++s)
      o4[tid + s * 128] = make_float4(v[s].x * inv, v[s].y * inv, v[s].z * inv, v[s].w * inv);
  }
}

extern "C" void kernel_launch(void* const* d_in, const int* in_sizes, int n_in,
                              void* d_out, int out_size, void* d_ws, size_t ws_size,
                              hipStream_t stream) {
  const float* inputs0 = (const float*)d_in[0];
  const float* logits0 = (const float*)d_in[1];
  const float* logits1 = (const float*)d_in[2];
  const int* targets = (const int*)d_in[3];
  const int* neighbors = (const int*)d_in[5];
  const float* ndist = (const float*)d_in[6];
  const float* rampup = (const float*)d_in[7];
  const float* features = (const float*)d_in[8];
  float* out = (float*)d_out;

  char* ws = (char*)d_ws;
  float* mll = (float*)(ws + 4096);            // 2 KB
  float* alpha = (float*)(ws + 8192);          // 2 KB (f32)
  float* tgt = (float*)(ws + 16384);           // 1 KB
  float* pm = (float*)(ws + 65536);            // 256 KB (256 rows x 256 stripes)
  float* pl = (float*)(ws + 65536 + 262144);   // 256 KB
  _Float16* xh = (_Float16*)(ws + (3 << 20));  // 1 MB
  _Float16* P = (_Float16*)(ws + (4 << 20));   // 8 MB (row-major raw exp)

  prep<<<768, 256, 0, stream>>>(inputs0, logits0, logits1, P, xh, alpha, mll, out);
  fused2<<<1536, 256, 0, stream>>>(xh, features, P, alpha, mll, logits0, logits1,
                                   targets, neighbors, ndist, rampup, out + 3,
                                   pm, pl, tgt, out);
  final_reduce<<<512, 128, 0, stream>>>(pm, pl, tgt, logits0, mll, targets,
                                        inputs0, features, out + 3, out);
}